// Round 3
// baseline (3796.552 us; speedup 1.0000x reference)
//
#include <hip/hip_runtime.h>
#include <stdint.h>

#define NN 2048
#define TT 365
#define DD 16
#define HH 64
#define NBLK 128      // 16 rows per block, 1 block/CU (LDS-bound)
#define NTHR 1024     // 16 waves
#define SMEM_BYTES 150016
#define QSLOT_U32 65536          // 64 cols x 2048 nodes bf16 = 256 KB per ring slot
#define SENT32 0xFFFFFFFFu       // bf16 NaN pair: unreachable for tanh output

typedef __attribute__((ext_vector_type(8))) short bf16x8;
typedef __attribute__((ext_vector_type(4))) float f32x4;
typedef __attribute__((ext_vector_type(4))) unsigned int u32x4;

__device__ __forceinline__ unsigned short f2bf(float f) {
  union { float f; uint32_t u; } z; z.f = f;
  uint32_t r = z.u + 0x7fffu + ((z.u >> 16) & 1u);
  return (unsigned short)(r >> 16);
}
__device__ __forceinline__ float sigmoid_(float x) { return 1.f / (1.f + __expf(-x)); }
__device__ __forceinline__ float tanh_(float x) {
  float ax = fabsf(x);
  float e = __expf(-2.f * ax);
  float r = (1.f - e) / (1.f + e);
  return x < 0.f ? -r : r;
}
__device__ __forceinline__ bf16x8 asbf(u32x4 v) { return __builtin_bit_cast(bf16x8, v); }

// R16: tag-in-data sync. Ring slots pre-filled with 0xFF sentinel (bf16 NaN,
// impossible for tanh output); publisher does ONE sc1 8B store and moves on —
// no vmcnt ack, flag is only a wake hint (stored without ordering). Consumer
// verifies arrival on the data itself (8B stores are atomic -> check words
// 0 and 2 of each 16B chunk) and retries only pending chunks via sc0sc1
// L3-direct loads (cached poll would deadlock on stale XCD-local L2).
// Gates-GEMM + epilogue + B1/B2 moved BEFORE the wait (depend only on h_{t-1}).
// Post-detect chain: phaseB MFMA -> reduce -> update -> qgemm -> store.
// Fallback (!ringfull): R15 flag+ack+fence path.
__global__ __launch_bounds__(NTHR) __attribute__((amdgpu_waves_per_eu(4, 4)))
void rgcn_persist(
    const float* __restrict__ X, const float* __restrict__ Af,
    const float* __restrict__ Wih, const float* __restrict__ Whh,
    const float* __restrict__ Bias, const float* __restrict__ Wq,
    const float* __restrict__ Bq, const float* __restrict__ Wd,
    const float* __restrict__ Bd, float* __restrict__ Out,
    uint32_t* qRing, uint32_t* flags, int rdepth, int ringfull)
{
  extern __shared__ __align__(16) char smem[];
  unsigned short* afrag = (unsigned short*)smem;                 // [64kc][64ln][8] 65536
  unsigned short* whxT  = (unsigned short*)(smem + 65536);       // [256n][104k]    53248
  unsigned short* wqT   = (unsigned short*)(smem + 118784);      // [64n][72k]       9216
  float*          sh_g  = (float*)(smem + 128000);               // [16][260] fp32  16640
  f32x4*          sh_part = (f32x4*)(smem + 128000);             // union (16384)
  unsigned short* sh_hx = (unsigned short*)(smem + 144640);      // [16][104] bf16   3328
  unsigned int*   cnt   = (unsigned int*)(smem + 147968);        // publish arrival ctr

  const int tid = threadIdx.x;
  const int w = tid >> 6;        // wave 0..15 (== node row for per-thread work)
  const int c = tid & 63;        // lane
  const int base = blockIdx.x * 16;
  const int m = c & 15, quad = c >> 4;
  const int nt = w & 3, kh = w >> 2;                       // phase B tile coords

  // ---- one-time staging ----
  for (int i = tid; i < 256 * 104; i += NTHR) {            // [WhhT | WihT | 0]
    int n = i / 104, k = i - n * 104;
    float v = (k < 64) ? Whh[k * 256 + n] : (k < 80) ? Wih[(k - 64) * 256 + n] : 0.f;
    whxT[i] = f2bf(v);
  }
  for (int i = tid; i < 64 * 72; i += NTHR) {              // WqT (pad k 64..71 = 0)
    int n = i / 72, k = i - n * 72;
    wqT[i] = (k < 64) ? f2bf(Wq[k * 64 + n]) : (unsigned short)0;
  }
  for (int i = tid; i < 16 * NN; i += NTHR) {              // A -> MFMA A-frag layout
    int r = i >> 11, k = i & (NN - 1);
    afrag[(k >> 5) * 512 + (((k >> 3) & 3) * 16 + r) * 8 + (k & 7)] =
        f2bf(Af[(size_t)(base + r) * NN + k]);
  }
  for (int i = tid; i < 16 * 104; i += NTHR) sh_hx[i] = 0; // h=0, x below, pad=0
  __syncthreads();
  if (c < 16) sh_hx[w * 104 + 64 + c] = f2bf(X[(size_t)(base + w) * (TT * DD) + c]);
  if (tid == 0) *cnt = 0u;
  __syncthreads();

  const float b_i = Bias[c], b_f = Bias[64 + c], b_g = Bias[128 + c], b_o = Bias[192 + c];
  const float wdc = Wd[c], bdc = Bd[0];
  const float bqv = (w < 4) ? Bq[w * 16 + m] : 0.f;        // q-GEMM col bias
  const unsigned short* afp = afrag + (kh * 16) * 512 + c * 8;

  float creg = 0.f, hreg = 0.f;

  // ---- initial publish: q_0 = tanh(b_q) -> ring slot 0 ----
  if (w < 4) {
    unsigned short qb = f2bf(tanh_(bqv));
    uint32_t pp = (uint32_t)qb | ((uint32_t)qb << 16);
    unsigned long long v = (unsigned long long)pp | ((unsigned long long)pp << 32);
    unsigned long long* dst =
        (unsigned long long*)(qRing + (size_t)(w * 16 + m) * (NN / 2) + (base >> 1) + 2 * quad);
    __hip_atomic_store(dst, v, __ATOMIC_RELAXED, __HIP_MEMORY_SCOPE_AGENT);
    if (!ringfull) asm volatile("s_waitcnt vmcnt(0)" ::: "memory");
    if (c == 0) {
      unsigned old = atomicAdd(cnt, 1u);
      if (old == 3u)
        __hip_atomic_store(&flags[blockIdx.x * 16], 1u,
                           __ATOMIC_RELAXED, __HIP_MEMORY_SCOPE_AGENT);
    }
  }

  int slotR = 0;                                           // read slot for step t
  for (int t = 0; t < TT; ++t) {
    const int slotW = (slotR + 1 == rdepth) ? 0 : slotR + 1;

    // ---- pre-wait work: depends only on h_{t-1}, x_t ----
    float xnext = 0.f;                     // prefetch x_{t+1}
    if (c < 16 && t < TT - 1)
      xnext = X[(size_t)(base + w) * (TT * DD) + (t + 1) * DD + c];

    f32x4 dg = {0.f, 0.f, 0.f, 0.f};       // gates-GEMM
    {
      const unsigned short* ar = sh_hx + m * 104 + quad * 8;
      const unsigned short* br = whxT + (w * 16 + m) * 104 + quad * 8;
      #pragma unroll
      for (int ch = 0; ch < 3; ++ch)
        dg = __builtin_amdgcn_mfma_f32_16x16x32_bf16(*(const bf16x8*)(ar + ch * 32),
                                                     *(const bf16x8*)(br + ch * 32), dg, 0, 0, 0);
    }
    #pragma unroll
    for (int r = 0; r < 4; ++r)            // D: row=quad*4+r, col=16w+m
      sh_g[(quad * 4 + r) * 260 + w * 16 + m] = dg[r];
    __syncthreads();                       // B1: sh_g ready

    float gi = sigmoid_(b_i + sh_g[w * 260 + c]);
    float gf = sigmoid_(b_f + sh_g[w * 260 + 64 + c]);
    float gg = tanh_  (b_g + sh_g[w * 260 + 128 + c]);
    float go = sigmoid_(b_o + sh_g[w * 260 + 192 + c]);
    __syncthreads();                       // B2: sh_g free for sh_part reuse

    // ---- flag wake-hint: my 32 source blocks issued q_t ----
    {
      const uint32_t target = (uint32_t)(t + 1);
      const int src = 32 * kh + (c & 31);                  // lanes 32..63 duplicate
      for (;;) {
        uint32_t f = __hip_atomic_load(&flags[src * 16],
                                       __ATOMIC_RELAXED, __HIP_MEMORY_SCOPE_AGENT);
        if (__all((int)(f >= target))) break;
        __builtin_amdgcn_s_sleep(1);
      }
    }
    if (!ringfull)                                         // slot reuse -> inv stale L2
      __builtin_amdgcn_fence(__ATOMIC_ACQUIRE, "agent");

    // ---- q acquire ----
    const unsigned short* qslot = (const unsigned short*)(qRing + (size_t)slotR * QSLOT_U32);
    const unsigned short* qrow = qslot + (size_t)(nt * 16 + m) * NN + kh * 512 + quad * 8;
    u32x4 qv[16];
    if (ringfull) {
      // sentinel-verified L3-direct loads; retry pending chunks only
      const uint64_t qa = (uint64_t)qrow;
      unsigned pend = 0xFFFFu;
      do {
#define QLD(i, offs) if (pend & (1u << i)) \
        asm volatile("global_load_dwordx4 %0, %1, off offset:" offs " sc0 sc1" \
                     : "=v"(qv[i]) : "v"(qa) : "memory")
        QLD(0,"0");    QLD(1,"64");   QLD(2,"128");  QLD(3,"192");
        QLD(4,"256");  QLD(5,"320");  QLD(6,"384");  QLD(7,"448");
        QLD(8,"512");  QLD(9,"576");  QLD(10,"640"); QLD(11,"704");
        QLD(12,"768"); QLD(13,"832"); QLD(14,"896"); QLD(15,"960");
#undef QLD
        asm volatile("s_waitcnt vmcnt(0)" ::: "memory");
        __builtin_amdgcn_sched_barrier(0);
        #pragma unroll
        for (int ch = 0; ch < 16; ++ch)
          if (pend & (1u << ch))
            if (qv[ch][0] != SENT32 && qv[ch][2] != SENT32)  // two 8B atomic halves
              pend &= ~(1u << ch);
      } while (!__all(pend == 0));
    } else {
      #pragma unroll
      for (int ch = 0; ch < 16; ++ch)
        qv[ch] = *(const u32x4*)(qrow + ch * 32);
    }

    // ---- phase B: Aq_t via MFMA ----
    f32x4 acc0 = {0.f,0.f,0.f,0.f}, acc1 = {0.f,0.f,0.f,0.f};
    #pragma unroll
    for (int ch = 0; ch < 16; ch += 2) {   // dual chain halves dep depth
      acc0 = __builtin_amdgcn_mfma_f32_16x16x32_bf16(
          *(const bf16x8*)(afp + ch * 512), asbf(qv[ch]), acc0, 0, 0, 0);
      acc1 = __builtin_amdgcn_mfma_f32_16x16x32_bf16(
          *(const bf16x8*)(afp + (ch + 1) * 512), asbf(qv[ch + 1]), acc1, 0, 0, 0);
    }
    sh_part[w * 64 + c] = acc0 + acc1;
    __syncthreads();                       // B3

    // conflict-free reduce: broadcast b128 reads, vector sum, uniform select
    f32x4 vs;
    {
      const f32x4* sp = sh_part;
      const int li = (w >> 2) * 16 + m;
      f32x4 p0 = sp[(0 * 4 + quad) * 64 + li];
      f32x4 p1 = sp[(1 * 4 + quad) * 64 + li];
      f32x4 p2 = sp[(2 * 4 + quad) * 64 + li];
      f32x4 p3 = sp[(3 * 4 + quad) * 64 + li];
      vs = (p0 + p1) + (p2 + p3);
    }
    float a01 = (w & 1) ? vs[1] : vs[0];
    float a23 = (w & 1) ? vs[3] : vs[2];
    float aqv = (w & 2) ? a23 : a01;

    // ---- update ----
    creg = gf * (creg + aqv) + gi * gg;
    hreg = go * tanh_(creg);
    sh_hx[w * 104 + c] = f2bf(hreg);
    if (c < 16) sh_hx[w * 104 + 64 + c] = f2bf(xnext);
    __syncthreads();                       // B4: h_t visible

    // ---- fused q-GEMM + publish into ring slot t+1 (no ack in ringfull) ----
    if (w < 4 && t < TT - 1) {
      f32x4 dq = {0.f, 0.f, 0.f, 0.f};
      const unsigned short* ar = sh_hx + m * 104 + quad * 8;
      const unsigned short* br = wqT + (w * 16 + m) * 72 + quad * 8;
      #pragma unroll
      for (int k2 = 0; k2 < 2; ++k2)
        dq = __builtin_amdgcn_mfma_f32_16x16x32_bf16(*(const bf16x8*)(ar + k2 * 32),
                                                     *(const bf16x8*)(br + k2 * 32), dq, 0, 0, 0);
      // D: row=quad*4+r (node), col=16w+m -> 4 consecutive nodes = one 8B store
      unsigned short b0 = f2bf(tanh_(dq[0] + bqv));
      unsigned short b1 = f2bf(tanh_(dq[1] + bqv));
      unsigned short b2 = f2bf(tanh_(dq[2] + bqv));
      unsigned short b3 = f2bf(tanh_(dq[3] + bqv));
      unsigned long long v =
          (unsigned long long)((uint32_t)b0 | ((uint32_t)b1 << 16)) |
          ((unsigned long long)((uint32_t)b2 | ((uint32_t)b3 << 16)) << 32);
      unsigned long long* dst =
          (unsigned long long*)(qRing + (size_t)slotW * QSLOT_U32 +
                                (size_t)(w * 16 + m) * (NN / 2) + (base >> 1) + 2 * quad);
      __hip_atomic_store(dst, v, __ATOMIC_RELAXED, __HIP_MEMORY_SCOPE_AGENT);
      if (!ringfull) asm volatile("s_waitcnt vmcnt(0)" ::: "memory");
      if (c == 0) {
        unsigned old = atomicAdd(cnt, 1u);                 // LDS arrival counter
        if (old == (unsigned)(4 * t + 7))                  // 4th wave of this step
          __hip_atomic_store(&flags[blockIdx.x * 16], (uint32_t)(t + 2),
                             __ATOMIC_RELAXED, __HIP_MEMORY_SCOPE_AGENT);
      }
    }

    // ---- output projection (off the publish critical path) ----
    float red = hreg * wdc;
    #pragma unroll
    for (int off = 32; off; off >>= 1) red += __shfl_xor(red, off);
    if (c == 0) {
      union { float f; uint32_t u; } o; o.f = red + bdc;
      __hip_atomic_store((uint32_t*)&Out[(size_t)(base + w) * TT + t], o.u,
                         __ATOMIC_RELAXED, __HIP_MEMORY_SCOPE_AGENT);
    }

    slotR = slotW;
  }
}

extern "C" void kernel_launch(void* const* d_in, const int* in_sizes, int n_in,
                              void* d_out, int out_size, void* d_ws, size_t ws_size,
                              hipStream_t stream) {
  const float* X    = (const float*)d_in[0];
  const float* Af   = (const float*)d_in[1];
  const float* Wih  = (const float*)d_in[2];
  const float* Whh  = (const float*)d_in[3];
  const float* Bias = (const float*)d_in[4];
  const float* Wq   = (const float*)d_in[5];
  const float* Bq   = (const float*)d_in[6];
  const float* Wd   = (const float*)d_in[7];
  const float* Bd   = (const float*)d_in[8];
  float* Out = (float*)d_out;

  char* ws = (char*)d_ws;
  uint32_t* flags = (uint32_t*)ws;                         // 128 flags, 64B apart (8 KB)
  uint32_t* qRing = (uint32_t*)(ws + 8192);                // R slots x 256 KB

  // one fresh slot per step if workspace allows (366 slots = 92 MB): write-once
  // ring => sentinel validity needs no reset and no slot-reuse fences.
  long long avail = (long long)ws_size - 8192;
  int rdepth = (int)(avail / (QSLOT_U32 * 4));
  if (rdepth > TT + 1) rdepth = TT + 1;
  if (rdepth < 2) rdepth = 2;                              // safety (ws >= 528 KB known)
  int ringfull = (rdepth >= TT + 1) ? 1 : 0;

  hipFuncSetAttribute((const void*)rgcn_persist,
                      hipFuncAttributeMaxDynamicSharedMemorySize, SMEM_BYTES);
  hipMemsetAsync(ws, 0, 8192, stream);                     // zero flags (poisoned 0xAA!)
  if (ringfull)                                            // sentinel-fill the ring
    hipMemsetAsync(qRing, 0xFF, (size_t)rdepth * QSLOT_U32 * 4, stream);
  hipLaunchKernelGGL(rgcn_persist, dim3(NBLK), dim3(NTHR), SMEM_BYTES, stream,
                     X, Af, Wih, Whh, Bias, Wq, Bq, Wd, Bd, Out, qRing, flags,
                     rdepth, ringfull);
}

// Round 4
// 3542.629 us; speedup vs baseline: 1.0717x; 1.0717x over previous
//
#include <hip/hip_runtime.h>
#include <stdint.h>

#define NN 2048
#define TT 365
#define DD 16
#define HH 64
#define NBLK 128      // 16 rows per block, 1 block/CU (LDS-bound)
#define NTHR 1024     // 16 waves
#define SMEM_BYTES 150016
#define QSLOT_U32 65536          // 64 cols x 2048 nodes bf16 = 256 KB per ring slot
#define SENT32 0xFFFFFFFFu       // bf16 NaN pair: unreachable for tanh output

typedef __attribute__((ext_vector_type(8))) short bf16x8;
typedef __attribute__((ext_vector_type(4))) float f32x4;
typedef __attribute__((ext_vector_type(4))) unsigned int u32x4;

__device__ __forceinline__ unsigned short f2bf(float f) {
  union { float f; uint32_t u; } z; z.f = f;
  uint32_t r = z.u + 0x7fffu + ((z.u >> 16) & 1u);
  return (unsigned short)(r >> 16);
}
__device__ __forceinline__ float sigmoid_(float x) { return 1.f / (1.f + __expf(-x)); }
__device__ __forceinline__ float tanh_(float x) {
  float ax = fabsf(x);
  float e = __expf(-2.f * ax);
  float r = (1.f - e) / (1.f + e);
  return x < 0.f ? -r : r;
}
__device__ __forceinline__ bf16x8 asbf(u32x4 v) { return __builtin_bit_cast(bf16x8, v); }

// R17: FLAG-FREE tag-in-data sync. R16 showed ~0.96 MB/step of HBM line-fetch
// traffic (and dur == hbm traffic / 146 GB/s) attributable to 2048 waves
// polling 128 flag lines — the one structure shared by all prior rounds.
// Now the q data itself is the only sync object: publisher issues ONE sc1 8B
// store per (col,node-quad) and moves on (no ack, no LDS counter, no flag);
// consumer retry-loads only pending 16B chunks (sentinel 0xFF = bf16 NaN,
// unreachable for tanh output) with s_sleep backoff. Skew is self-bounded at
// <=1 step by the data dependence; the ring is write-once so no reuse hazard.
// sh_part padded [16][65] f32x4 (kills residual LDS bank conflicts; same size
// as sh_g union partner). Fallback (!ringfull): R16 flag+ack+fence protocol.
__global__ __launch_bounds__(NTHR) __attribute__((amdgpu_waves_per_eu(4, 4)))
void rgcn_persist(
    const float* __restrict__ X, const float* __restrict__ Af,
    const float* __restrict__ Wih, const float* __restrict__ Whh,
    const float* __restrict__ Bias, const float* __restrict__ Wq,
    const float* __restrict__ Bq, const float* __restrict__ Wd,
    const float* __restrict__ Bd, float* __restrict__ Out,
    uint32_t* qRing, uint32_t* flags, int rdepth, int ringfull)
{
  extern __shared__ __align__(16) char smem[];
  unsigned short* afrag = (unsigned short*)smem;                 // [64kc][64ln][8] 65536
  unsigned short* whxT  = (unsigned short*)(smem + 65536);       // [256n][104k]    53248
  unsigned short* wqT   = (unsigned short*)(smem + 118784);      // [64n][72k]       9216
  float*          sh_g  = (float*)(smem + 128000);               // [16][260] fp32  16640
  f32x4*          sh_part = (f32x4*)(smem + 128000);             // union [16][65] 16640
  unsigned short* sh_hx = (unsigned short*)(smem + 144640);      // [16][104] bf16   3328
  unsigned int*   cnt   = (unsigned int*)(smem + 147968);        // fallback arrival ctr

  const int tid = threadIdx.x;
  const int w = tid >> 6;        // wave 0..15 (== node row for per-thread work)
  const int c = tid & 63;        // lane
  const int base = blockIdx.x * 16;
  const int m = c & 15, quad = c >> 4;
  const int nt = w & 3, kh = w >> 2;                       // phase B tile coords

  // ---- one-time staging ----
  for (int i = tid; i < 256 * 104; i += NTHR) {            // [WhhT | WihT | 0]
    int n = i / 104, k = i - n * 104;
    float v = (k < 64) ? Whh[k * 256 + n] : (k < 80) ? Wih[(k - 64) * 256 + n] : 0.f;
    whxT[i] = f2bf(v);
  }
  for (int i = tid; i < 64 * 72; i += NTHR) {              // WqT (pad k 64..71 = 0)
    int n = i / 72, k = i - n * 72;
    wqT[i] = (k < 64) ? f2bf(Wq[k * 64 + n]) : (unsigned short)0;
  }
  for (int i = tid; i < 16 * NN; i += NTHR) {              // A -> MFMA A-frag layout
    int r = i >> 11, k = i & (NN - 1);
    afrag[(k >> 5) * 512 + (((k >> 3) & 3) * 16 + r) * 8 + (k & 7)] =
        f2bf(Af[(size_t)(base + r) * NN + k]);
  }
  for (int i = tid; i < 16 * 104; i += NTHR) sh_hx[i] = 0; // h=0, x below, pad=0
  __syncthreads();
  if (c < 16) sh_hx[w * 104 + 64 + c] = f2bf(X[(size_t)(base + w) * (TT * DD) + c]);
  if (tid == 0) *cnt = 0u;
  __syncthreads();

  const float b_i = Bias[c], b_f = Bias[64 + c], b_g = Bias[128 + c], b_o = Bias[192 + c];
  const float wdc = Wd[c], bdc = Bd[0];
  const float bqv = (w < 4) ? Bq[w * 16 + m] : 0.f;        // q-GEMM col bias
  const unsigned short* afp = afrag + (kh * 16) * 512 + c * 8;

  float creg = 0.f, hreg = 0.f;

  // ---- initial publish: q_0 = tanh(b_q) -> ring slot 0 ----
  if (w < 4) {
    unsigned short qb = f2bf(tanh_(bqv));
    uint32_t pp = (uint32_t)qb | ((uint32_t)qb << 16);
    unsigned long long v = (unsigned long long)pp | ((unsigned long long)pp << 32);
    unsigned long long* dst =
        (unsigned long long*)(qRing + (size_t)(w * 16 + m) * (NN / 2) + (base >> 1) + 2 * quad);
    __hip_atomic_store(dst, v, __ATOMIC_RELAXED, __HIP_MEMORY_SCOPE_AGENT);
    if (!ringfull) {
      asm volatile("s_waitcnt vmcnt(0)" ::: "memory");
      if (c == 0) {
        unsigned old = atomicAdd(cnt, 1u);
        if (old == 3u)
          __hip_atomic_store(&flags[blockIdx.x * 16], 1u,
                             __ATOMIC_RELAXED, __HIP_MEMORY_SCOPE_AGENT);
      }
    }
  }

  int slotR = 0;                                           // read slot for step t
  for (int t = 0; t < TT; ++t) {
    const int slotW = (slotR + 1 == rdepth) ? 0 : slotR + 1;

    // ---- pre-wait work: depends only on h_{t-1}, x_t ----
    float xnext = 0.f;                     // prefetch x_{t+1}
    if (c < 16 && t < TT - 1)
      xnext = X[(size_t)(base + w) * (TT * DD) + (t + 1) * DD + c];

    f32x4 dg = {0.f, 0.f, 0.f, 0.f};       // gates-GEMM
    {
      const unsigned short* ar = sh_hx + m * 104 + quad * 8;
      const unsigned short* br = whxT + (w * 16 + m) * 104 + quad * 8;
      #pragma unroll
      for (int ch = 0; ch < 3; ++ch)
        dg = __builtin_amdgcn_mfma_f32_16x16x32_bf16(*(const bf16x8*)(ar + ch * 32),
                                                     *(const bf16x8*)(br + ch * 32), dg, 0, 0, 0);
    }
    #pragma unroll
    for (int r = 0; r < 4; ++r)            // D: row=quad*4+r, col=16w+m
      sh_g[(quad * 4 + r) * 260 + w * 16 + m] = dg[r];
    __syncthreads();                       // B1: sh_g ready

    float gi = sigmoid_(b_i + sh_g[w * 260 + c]);
    float gf = sigmoid_(b_f + sh_g[w * 260 + 64 + c]);
    float gg = tanh_  (b_g + sh_g[w * 260 + 128 + c]);
    float go = sigmoid_(b_o + sh_g[w * 260 + 192 + c]);
    __syncthreads();                       // B2: sh_g free for sh_part reuse

    // ---- q acquire ----
    const unsigned short* qslot = (const unsigned short*)(qRing + (size_t)slotR * QSLOT_U32);
    const unsigned short* qrow = qslot + (size_t)(nt * 16 + m) * NN + kh * 512 + quad * 8;
    u32x4 qv[16];
    if (ringfull) {
      // flag-free: sentinel-verified L3-direct loads; retry pending chunks only
      const uint64_t qa = (uint64_t)qrow;
      unsigned pend = 0xFFFFu;
      int pass = 0;
      do {
        if (pass) __builtin_amdgcn_s_sleep(2);             // backoff, throttle L3
#define QLD(i, offs) if (pend & (1u << i)) \
        asm volatile("global_load_dwordx4 %0, %1, off offset:" offs " sc0 sc1" \
                     : "=v"(qv[i]) : "v"(qa) : "memory")
        QLD(0,"0");    QLD(1,"64");   QLD(2,"128");  QLD(3,"192");
        QLD(4,"256");  QLD(5,"320");  QLD(6,"384");  QLD(7,"448");
        QLD(8,"512");  QLD(9,"576");  QLD(10,"640"); QLD(11,"704");
        QLD(12,"768"); QLD(13,"832"); QLD(14,"896"); QLD(15,"960");
#undef QLD
        asm volatile("s_waitcnt vmcnt(0)" ::: "memory");
        __builtin_amdgcn_sched_barrier(0);
        #pragma unroll
        for (int ch = 0; ch < 16; ++ch)
          if (pend & (1u << ch))
            if (qv[ch][0] != SENT32 && qv[ch][2] != SENT32)  // two 8B atomic halves
              pend &= ~(1u << ch);
        pass = 1;
      } while (!__all(pend == 0));
    } else {
      // fallback: flag wait + fence + plain loads
      const uint32_t target = (uint32_t)(t + 1);
      const int src = 32 * kh + (c & 31);                  // lanes 32..63 duplicate
      for (;;) {
        uint32_t f = __hip_atomic_load(&flags[src * 16],
                                       __ATOMIC_RELAXED, __HIP_MEMORY_SCOPE_AGENT);
        if (__all((int)(f >= target))) break;
        __builtin_amdgcn_s_sleep(1);
      }
      __builtin_amdgcn_fence(__ATOMIC_ACQUIRE, "agent");   // slot reuse -> inv stale L2
      #pragma unroll
      for (int ch = 0; ch < 16; ++ch)
        qv[ch] = *(const u32x4*)(qrow + ch * 32);
    }

    // ---- phase B: Aq_t via MFMA ----
    f32x4 acc0 = {0.f,0.f,0.f,0.f}, acc1 = {0.f,0.f,0.f,0.f};
    #pragma unroll
    for (int ch = 0; ch < 16; ch += 2) {   // dual chain halves dep depth
      acc0 = __builtin_amdgcn_mfma_f32_16x16x32_bf16(
          *(const bf16x8*)(afp + ch * 512), asbf(qv[ch]), acc0, 0, 0, 0);
      acc1 = __builtin_amdgcn_mfma_f32_16x16x32_bf16(
          *(const bf16x8*)(afp + (ch + 1) * 512), asbf(qv[ch + 1]), acc1, 0, 0, 0);
    }
    sh_part[w * 65 + c] = acc0 + acc1;     // [16][65] padded stride
    __syncthreads();                       // B3

    // conflict-free reduce: broadcast b128 reads, vector sum, uniform select
    f32x4 vs;
    {
      const f32x4* sp = sh_part;
      const int li = (w >> 2) * 16 + m;
      f32x4 p0 = sp[(0 * 4 + quad) * 65 + li];
      f32x4 p1 = sp[(1 * 4 + quad) * 65 + li];
      f32x4 p2 = sp[(2 * 4 + quad) * 65 + li];
      f32x4 p3 = sp[(3 * 4 + quad) * 65 + li];
      vs = (p0 + p1) + (p2 + p3);
    }
    float a01 = (w & 1) ? vs[1] : vs[0];
    float a23 = (w & 1) ? vs[3] : vs[2];
    float aqv = (w & 2) ? a23 : a01;

    // ---- update ----
    creg = gf * (creg + aqv) + gi * gg;
    hreg = go * tanh_(creg);
    sh_hx[w * 104 + c] = f2bf(hreg);
    if (c < 16) sh_hx[w * 104 + 64 + c] = f2bf(xnext);
    __syncthreads();                       // B4: h_t visible

    // ---- fused q-GEMM + publish into ring slot t+1 ----
    if (w < 4 && t < TT - 1) {
      f32x4 dq = {0.f, 0.f, 0.f, 0.f};
      const unsigned short* ar = sh_hx + m * 104 + quad * 8;
      const unsigned short* br = wqT + (w * 16 + m) * 72 + quad * 8;
      #pragma unroll
      for (int k2 = 0; k2 < 2; ++k2)
        dq = __builtin_amdgcn_mfma_f32_16x16x32_bf16(*(const bf16x8*)(ar + k2 * 32),
                                                     *(const bf16x8*)(br + k2 * 32), dq, 0, 0, 0);
      // D: row=quad*4+r (node), col=16w+m -> 4 consecutive nodes = one 8B store
      unsigned short b0 = f2bf(tanh_(dq[0] + bqv));
      unsigned short b1 = f2bf(tanh_(dq[1] + bqv));
      unsigned short b2 = f2bf(tanh_(dq[2] + bqv));
      unsigned short b3 = f2bf(tanh_(dq[3] + bqv));
      unsigned long long v =
          (unsigned long long)((uint32_t)b0 | ((uint32_t)b1 << 16)) |
          ((unsigned long long)((uint32_t)b2 | ((uint32_t)b3 << 16)) << 32);
      unsigned long long* dst =
          (unsigned long long*)(qRing + (size_t)slotW * QSLOT_U32 +
                                (size_t)(w * 16 + m) * (NN / 2) + (base >> 1) + 2 * quad);
      __hip_atomic_store(dst, v, __ATOMIC_RELAXED, __HIP_MEMORY_SCOPE_AGENT);
      if (!ringfull) {                     // fallback needs ack + flag
        asm volatile("s_waitcnt vmcnt(0)" ::: "memory");
        if (c == 0) {
          unsigned old = atomicAdd(cnt, 1u);
          if (old == (unsigned)(4 * t + 7))
            __hip_atomic_store(&flags[blockIdx.x * 16], (uint32_t)(t + 2),
                               __ATOMIC_RELAXED, __HIP_MEMORY_SCOPE_AGENT);
        }
      }
    }

    // ---- output projection (off the publish critical path) ----
    float red = hreg * wdc;
    #pragma unroll
    for (int off = 32; off; off >>= 1) red += __shfl_xor(red, off);
    if (c == 0) {
      union { float f; uint32_t u; } o; o.f = red + bdc;
      __hip_atomic_store((uint32_t*)&Out[(size_t)(base + w) * TT + t], o.u,
                         __ATOMIC_RELAXED, __HIP_MEMORY_SCOPE_AGENT);
    }

    slotR = slotW;
  }
}

extern "C" void kernel_launch(void* const* d_in, const int* in_sizes, int n_in,
                              void* d_out, int out_size, void* d_ws, size_t ws_size,
                              hipStream_t stream) {
  const float* X    = (const float*)d_in[0];
  const float* Af   = (const float*)d_in[1];
  const float* Wih  = (const float*)d_in[2];
  const float* Whh  = (const float*)d_in[3];
  const float* Bias = (const float*)d_in[4];
  const float* Wq   = (const float*)d_in[5];
  const float* Bq   = (const float*)d_in[6];
  const float* Wd   = (const float*)d_in[7];
  const float* Bd   = (const float*)d_in[8];
  float* Out = (float*)d_out;

  char* ws = (char*)d_ws;
  uint32_t* flags = (uint32_t*)ws;                         // 128 flags, 64B apart (8 KB)
  uint32_t* qRing = (uint32_t*)(ws + 8192);                // R slots x 256 KB

  // one fresh slot per step if workspace allows (366 slots = 92 MB): write-once
  // ring => sentinel validity needs no reset and no slot-reuse fences.
  long long avail = (long long)ws_size - 8192;
  int rdepth = (int)(avail / (QSLOT_U32 * 4));
  if (rdepth > TT + 1) rdepth = TT + 1;
  if (rdepth < 2) rdepth = 2;                              // safety (ws >= 528 KB known)
  int ringfull = (rdepth >= TT + 1) ? 1 : 0;

  hipFuncSetAttribute((const void*)rgcn_persist,
                      hipFuncAttributeMaxDynamicSharedMemorySize, SMEM_BYTES);
  hipMemsetAsync(ws, 0, 8192, stream);                     // zero flags (poisoned 0xAA!)
  if (ringfull)                                            // sentinel-fill the ring
    hipMemsetAsync(qRing, 0xFF, (size_t)rdepth * QSLOT_U32 * 4, stream);
  hipLaunchKernelGGL(rgcn_persist, dim3(NBLK), dim3(NTHR), SMEM_BYTES, stream,
                     X, Af, Wih, Whh, Bias, Wq, Bq, Wd, Bd, Out, qRing, flags,
                     rdepth, ringfull);
}